// Round 3
// baseline (237.972 us; speedup 1.0000x reference)
//
#include <hip/hip_runtime.h>
#include <hip/hip_bf16.h>

// NeighborAttention on MI355X. ALL floating tensors are fp32 (per reference);
// mask is int32. Output fp32.
// KEY INSIGHT: query = broadcast of masked neighbor-mean -> all seq positions
// share one query per (b,h). Attention collapses:
//   scores[b,h,s] = x[b,s,:] . p[b,h,:],  p[b,h,:] = sum_j q[b,h,j]*kw[h*64+j,:]
//   (q.kb constant is softmax-invariant -> dropped)
//   ctx[b,h*64+j] = (sum_s w[b,h,s]*x[b,s,:]) . vw[h*64+j,:] + vb   (sum_s w = 1)
//   out_row[b]    = ctx[b] @ ow.T + ob       (same for all s)
//   out[b,s,:]    = LayerNorm(out_row[b] + x[b,s,:]) * g + beta
// -> no 8192x1024x1024 GEMMs; ~0.6 GFLOP + ~170 MB fp32 traffic.
// R2 fix: R0/R1 read fp32 buffers as bf16 -> garbage (incl. NaN encodings) ->
// NaN through softmax. This round: fp32 loads everywhere + float4 in k_ln/k_scores.

#define DIM  1024
#define NH   16
#define HD   64
#define BS   8
#define SEQ  1024
#define NNB  50

// ---------------- K0: zero xw (atomic destination) ----------------
__global__ void k_zero(float* __restrict__ buf){
  int i = blockIdx.x*1024 + threadIdx.x;
  #pragma unroll
  for (int k=0; k<4; k++) buf[i + 256*k] = 0.f;
}

// ---------------- K1: masked neighbor mean pool: xn[b,d] ----------------
__global__ void k_pool(const float* __restrict__ xnb, const float* __restrict__ nm,
                       float* __restrict__ xn){
  int b = blockIdx.x;
  int d = blockIdx.y*256 + threadIdx.x;
  float acc = 0.f, wsum = 0.f;
  for (int n=0; n<NNB; n++){
    float w = nm[b*NNB + n];
    acc  += w * xnb[(size_t)(b*NNB + n)*DIM + d];
    wsum += w;
  }
  xn[b*DIM + d] = acc / wsum;
}

// ---------------- K2: q[b,j] = (xn[b,:].qw[j,:] + qb[j]) / 8 ----------------
__global__ void k_q(const float* __restrict__ xn, const float* __restrict__ qw,
                    const float* __restrict__ qb, float* __restrict__ q){
  int wv = threadIdx.x >> 6, ln = threadIdx.x & 63;
  int j = blockIdx.x*4 + wv;
  float acc[BS] = {0,0,0,0,0,0,0,0};
  for (int i=0; i<16; i++){
    int d = ln + 64*i;
    float wt = qw[(size_t)j*DIM + d];
    #pragma unroll
    for (int b=0; b<BS; b++) acc[b] += wt * xn[b*DIM + d];
  }
  #pragma unroll
  for (int off=32; off>=1; off>>=1){
    #pragma unroll
    for (int b=0; b<BS; b++) acc[b] += __shfl_down(acc[b], off, 64);
  }
  if (ln == 0){
    float bias = qb[j];
    #pragma unroll
    for (int b=0; b<BS; b++) q[b*DIM + j] = (acc[b] + bias) * 0.125f;
  }
}

// ---------------- K3: p[b,h,d] = sum_j q[b,h*64+j]*kw[h*64+j,d] ----------------
__global__ void k_p(const float* __restrict__ q, const float* __restrict__ kw,
                    float* __restrict__ p){
  int h = blockIdx.x;
  int d = blockIdx.y*256 + threadIdx.x;
  float acc[BS] = {0,0,0,0,0,0,0,0};
  for (int j=0; j<HD; j++){
    float kv = kw[(size_t)(h*HD + j)*DIM + d];
    #pragma unroll
    for (int b=0; b<BS; b++) acc[b] += q[b*DIM + h*HD + j] * kv;
  }
  #pragma unroll
  for (int b=0; b<BS; b++) p[(size_t)(b*NH + h)*DIM + d] = acc[b];
}

// ---------------- K4: sc[b,h,s] = x[b,s,:].p[b,h,:]  (full K inside)
// grid (sc=16, b=8), block 256. Tile: 64 s x 16 h; K chunked 4x256, sub 4x64.
__global__ void k_scores(const float* __restrict__ x, const float* __restrict__ p,
                         float* __restrict__ sc){
  int s0 = blockIdx.x * 64;
  int b  = blockIdx.y;
  int tid = threadIdx.x;
  __shared__ float4 plds[256*5];      // [d][h/4] transposed p chunk, pad 5
  __shared__ float  xlds[64*65];      // [s][d] x tile, pad 65
  float* pf = (float*)plds;
  int s = tid & 63, g = tid >> 6;     // g = wave -> heads g*4..g*4+3 (wave-uniform)
  float acc[4] = {0.f,0.f,0.f,0.f};
  for (int kc=0; kc<4; kc++){
    int kbase = kc*256;
    __syncthreads();                  // prior compute done before restaging plds
    #pragma unroll
    for (int it=0; it<16; it++){      // stage p chunk: 256 d x 16 h
      int idx = it*256 + tid;
      int d = idx & 255, h = idx >> 8;
      pf[d*20 + h] = p[(size_t)(b*NH + h)*DIM + kbase + d];
    }
    for (int dk=0; dk<4; dk++){
      __syncthreads();                // plds staged / prior xlds reads done
      #pragma unroll
      for (int it=0; it<4; it++){     // stage x tile 64 s x 64 d (float4 loads)
        int idx = it*256 + tid;       // 0..1023
        int dd4 = idx & 15, ss = idx >> 4;
        float4 v = *(const float4*)(x + (size_t)(b*SEQ + s0 + ss)*DIM + kbase + dk*64 + dd4*4);
        int o = ss*65 + dd4*4;
        xlds[o] = v.x; xlds[o+1] = v.y; xlds[o+2] = v.z; xlds[o+3] = v.w;
      }
      __syncthreads();
      #pragma unroll 8
      for (int dd=0; dd<64; dd++){
        float  xv = xlds[s*65 + dd];             // conflict-free (65 odd)
        float4 pv = plds[(dk*64 + dd)*5 + g];    // wave-uniform -> LDS broadcast
        acc[0] += xv*pv.x; acc[1] += xv*pv.y; acc[2] += xv*pv.z; acc[3] += xv*pv.w;
      }
    }
  }
  #pragma unroll
  for (int u=0; u<4; u++)
    sc[(size_t)(b*NH + g*4 + u)*SEQ + s0 + s] = acc[u];
}

// ---------------- K5: in-place softmax over s per (b,h) ----------------
__global__ void k_softmax(float* __restrict__ sc, const int* __restrict__ mask){
  int b = blockIdx.x >> 4, h = blockIdx.x & 15;
  int tid = threadIdx.x;
  float v[4];
  float mx = -3e38f;
  #pragma unroll
  for (int i=0; i<4; i++){
    int s = tid + 256*i;
    float v0 = sc[(size_t)(b*NH + h)*SEQ + s];
    if (mask[b*SEQ + s] == 0) v0 = -1e30f;
    v[i] = v0;
    mx = fmaxf(mx, v0);
  }
  #pragma unroll
  for (int off=32; off>=1; off>>=1) mx = fmaxf(mx, __shfl_xor(mx, off, 64));
  __shared__ float r1[4], r2[4];
  int wv = tid >> 6, ln = tid & 63;
  if (ln == 0) r1[wv] = mx;
  __syncthreads();
  mx = fmaxf(fmaxf(r1[0], r1[1]), fmaxf(r1[2], r1[3]));
  float sum = 0.f;
  #pragma unroll
  for (int i=0; i<4; i++){ v[i] = __expf(v[i] - mx); sum += v[i]; }
  #pragma unroll
  for (int off=32; off>=1; off>>=1) sum += __shfl_xor(sum, off, 64);
  if (ln == 0) r2[wv] = sum;
  __syncthreads();
  sum = r2[0] + r2[1] + r2[2] + r2[3];
  float inv = 1.f / sum;
  #pragma unroll
  for (int i=0; i<4; i++) sc[(size_t)(b*NH + h)*SEQ + tid + 256*i] = v[i] * inv;
}

// ---------------- K6: xw[b,h,d] += sum_{s in chunk} w[b,h,s]*x[b,s,d] (atomic)
// grid (dc=8, b=8, sc=8), block 256. Tile: 16 h x 128 d, s-chunk 128.
__global__ void k_wpool(const float* __restrict__ x, const float* __restrict__ w,
                        float* __restrict__ xw){
  int dc = blockIdx.x, b = blockIdx.y, scn = blockIdx.z;
  int tid = threadIdx.x;
  __shared__ float4 wlds[128*5];      // [s][h/4] transposed weights, pad 5
  float* wf = (float*)wlds;
  #pragma unroll
  for (int it=0; it<8; it++){
    int idx = it*256 + tid;
    int hh = idx >> 7, ss = idx & 127;
    wf[ss*20 + hh] = w[(size_t)(b*NH + hh)*SEQ + scn*128 + ss];
  }
  __syncthreads();
  int d  = dc*128 + (tid & 127);
  int hg = tid >> 7;                  // 0/1 -> heads hg*8..hg*8+7 (wave-uniform)
  float acc[8] = {0,0,0,0,0,0,0,0};
  #pragma unroll 4
  for (int s=0; s<128; s++){
    float  xv = x[(size_t)(b*SEQ + scn*128 + s)*DIM + d];
    float4 wa = wlds[s*5 + hg*2];     // wave-uniform -> broadcast
    float4 wb = wlds[s*5 + hg*2 + 1];
    acc[0]+=xv*wa.x; acc[1]+=xv*wa.y; acc[2]+=xv*wa.z; acc[3]+=xv*wa.w;
    acc[4]+=xv*wb.x; acc[5]+=xv*wb.y; acc[6]+=xv*wb.z; acc[7]+=xv*wb.w;
  }
  #pragma unroll
  for (int i=0; i<8; i++)
    atomicAdd(&xw[(size_t)(b*NH + hg*8 + i)*DIM + d], acc[i]);
}

// ---------------- K7: ctx[b,jo] = xw[b,h(jo),:].vw[jo,:] + vb[jo] ----------------
__global__ void k_ctx(const float* __restrict__ xw, const float* __restrict__ vw,
                      const float* __restrict__ vb, float* __restrict__ ctx){
  int wv = threadIdx.x >> 6, ln = threadIdx.x & 63;
  int jo = blockIdx.x*4 + wv;
  int h  = jo >> 6;
  float acc[BS] = {0,0,0,0,0,0,0,0};
  for (int i=0; i<16; i++){
    int d = ln + 64*i;
    float vv = vw[(size_t)jo*DIM + d];
    #pragma unroll
    for (int b=0; b<BS; b++) acc[b] += xw[(size_t)(b*NH + h)*DIM + d] * vv;
  }
  #pragma unroll
  for (int off=32; off>=1; off>>=1){
    #pragma unroll
    for (int b=0; b<BS; b++) acc[b] += __shfl_down(acc[b], off, 64);
  }
  if (ln == 0){
    float bias = vb[jo];
    #pragma unroll
    for (int b=0; b<BS; b++) ctx[b*DIM + jo] = acc[b] + bias;
  }
}

// ---------------- K8: out_row[b,i] = ctx[b,:].ow[i,:] + ob[i] ----------------
__global__ void k_outrow(const float* __restrict__ ctx, const float* __restrict__ ow,
                         const float* __restrict__ ob, float* __restrict__ outr){
  int wv = threadIdx.x >> 6, ln = threadIdx.x & 63;
  int io = blockIdx.x*4 + wv;
  float acc[BS] = {0,0,0,0,0,0,0,0};
  for (int i=0; i<16; i++){
    int d = ln + 64*i;
    float wt = ow[(size_t)io*DIM + d];
    #pragma unroll
    for (int b=0; b<BS; b++) acc[b] += ctx[b*DIM + d] * wt;
  }
  #pragma unroll
  for (int off=32; off>=1; off>>=1){
    #pragma unroll
    for (int b=0; b<BS; b++) acc[b] += __shfl_down(acc[b], off, 64);
  }
  if (ln == 0){
    float bias = ob[io];
    #pragma unroll
    for (int b=0; b<BS; b++) outr[b*DIM + io] = acc[b] + bias;
  }
}

// ---------------- K9: out[b,s,:] = LN(out_row[b]+x[b,s,:])*g + beta ----------------
// one row per block; float4 (16B/lane) loads+stores
__global__ void k_ln(const float* __restrict__ x, const float* __restrict__ outr,
                     const float* __restrict__ g, const float* __restrict__ bt,
                     float* __restrict__ out){
  int row = blockIdx.x;
  int b = row >> 10;
  size_t base = (size_t)row * DIM;
  int tid = threadIdx.x;
  float4 xv = ((const float4*)(x + base))[tid];
  float4 ov = ((const float4*)(outr + (size_t)b*DIM))[tid];
  float4 h;
  h.x = xv.x + ov.x; h.y = xv.y + ov.y; h.z = xv.z + ov.z; h.w = xv.w + ov.w;
  float s  = h.x + h.y + h.z + h.w;
  float s2 = h.x*h.x + h.y*h.y + h.z*h.z + h.w*h.w;
  #pragma unroll
  for (int off=32; off>=1; off>>=1){
    s  += __shfl_xor(s,  off, 64);
    s2 += __shfl_xor(s2, off, 64);
  }
  __shared__ float r1[4], r2[4];
  int wv = tid >> 6, ln = tid & 63;
  if (ln == 0){ r1[wv] = s; r2[wv] = s2; }
  __syncthreads();
  s  = r1[0] + r1[1] + r1[2] + r1[3];
  s2 = r2[0] + r2[1] + r2[2] + r2[3];
  float mu   = s  * (1.f/1024.f);
  float var  = s2 * (1.f/1024.f) - mu*mu;
  float rstd = rsqrtf(var + 1e-12f);
  float4 gv = ((const float4*)g)[tid];
  float4 bv = ((const float4*)bt)[tid];
  float4 y;
  y.x = (h.x - mu)*rstd*gv.x + bv.x;
  y.y = (h.y - mu)*rstd*gv.y + bv.y;
  y.z = (h.z - mu)*rstd*gv.z + bv.z;
  y.w = (h.w - mu)*rstd*gv.w + bv.w;
  ((float4*)(out + base))[tid] = y;
}

extern "C" void kernel_launch(void* const* d_in, const int* in_sizes, int n_in,
                              void* d_out, int out_size, void* d_ws, size_t ws_size,
                              hipStream_t stream) {
  const float* x    = (const float*)d_in[0];
  const float* xnb  = (const float*)d_in[1];
  const int*   mask = (const int*  )d_in[2];
  const float* nm   = (const float*)d_in[3];
  const float* qw   = (const float*)d_in[4];
  const float* qb   = (const float*)d_in[5];
  const float* kw   = (const float*)d_in[6];
  // d_in[7] = kb: additive constant per (b,h) on scores -> softmax-invariant, unused
  const float* vw   = (const float*)d_in[8];
  const float* vb   = (const float*)d_in[9];
  const float* ow   = (const float*)d_in[10];
  const float* ob   = (const float*)d_in[11];
  const float* lng  = (const float*)d_in[12];
  const float* lnb  = (const float*)d_in[13];
  float* out = (float*)d_out;

  float* ws   = (float*)d_ws;              // 425,984 floats = 1.63 MB total
  float* xn   = ws;                        // 8192
  float* q    = ws + 8192;                 // 8192
  float* p    = ws + 16384;                // 131072
  float* sc   = ws + 147456;               // 131072 (scores, softmax in-place)
  float* xw   = ws + 278528;               // 131072 (atomic accum)
  float* ctx  = ws + 409600;               // 8192
  float* outr = ws + 417792;               // 8192

  k_zero   <<<128,           256, 0, stream>>>(xw);
  k_pool   <<<dim3(BS,4),    256, 0, stream>>>(xnb, nm, xn);
  k_q      <<<256,           256, 0, stream>>>(xn, qw, qb, q);
  k_p      <<<dim3(NH,4),    256, 0, stream>>>(q, kw, p);
  k_scores <<<dim3(16,BS),   256, 0, stream>>>(x, p, sc);
  k_softmax<<<BS*NH,         256, 0, stream>>>(sc, mask);
  k_wpool  <<<dim3(8,BS,8),  256, 0, stream>>>(x, sc, xw);
  k_ctx    <<<256,           256, 0, stream>>>(xw, vw, vb, ctx);
  k_outrow <<<256,           256, 0, stream>>>(ctx, ow, ob, outr);
  k_ln     <<<BS*SEQ,        256, 0, stream>>>(x, outr, lng, lnb, out);
}

// Round 4
// 199.294 us; speedup vs baseline: 1.1941x; 1.1941x over previous
//
#include <hip/hip_runtime.h>
#include <hip/hip_bf16.h>

// NeighborAttention on MI355X. fp32 in/out, int32 mask.
// KEY INSIGHT: query = broadcast of masked neighbor-mean -> all seq positions
// share one query per (b,h). Attention collapses:
//   scores[b,h,s] = x[b,s,:] . p[b,h,:],  p[b,h,:] = sum_j q[b,h,j]*kw[h*64+j,:]
//   (q.kb constant is softmax-invariant -> dropped)
//   ctx[b,h*64+j] = (sum_s w[b,h,s]*x[b,s,:]) . vw[h*64+j,:] + vb   (sum_s w = 1)
//   out_row[b]    = ctx[b] @ ow.T + ob       (same for all s)
//   out[b,s,:]    = LayerNorm(out_row[b] + x[b,s,:]) * g + beta
// R3: occupancy fixes. k_scores was 74us at 5% occupancy (128 blocks = 2
// waves/CU). Now K-split x4 (512 blocks) + atomicAdd partials + b128 LDS
// reads. k_wpool rebuilt with float4 x loads. k_p 64->512 blocks.

#define DIM  1024
#define NH   16
#define HD   64
#define BS   8
#define SEQ  1024
#define NNB  50

// ---------------- K0: zero atomic destinations (sc + xw, contiguous) --------
__global__ void k_zero(float* __restrict__ buf){
  int i = blockIdx.x*1024 + threadIdx.x;
  #pragma unroll
  for (int k=0; k<4; k++) buf[i + 256*k] = 0.f;
}

// ---------------- K1: masked neighbor mean pool: xn[b,d] ----------------
__global__ void k_pool(const float* __restrict__ xnb, const float* __restrict__ nm,
                       float* __restrict__ xn){
  int b = blockIdx.x;
  int d = threadIdx.x*4;
  float4 acc = {0,0,0,0}; float wsum = 0.f;
  for (int n=0; n<NNB; n++){
    float w = nm[b*NNB + n];
    float4 v = *(const float4*)(xnb + (size_t)(b*NNB + n)*DIM + d);
    acc.x += w*v.x; acc.y += w*v.y; acc.z += w*v.z; acc.w += w*v.w;
    wsum += w;
  }
  float inv = 1.f/wsum;
  acc.x*=inv; acc.y*=inv; acc.z*=inv; acc.w*=inv;
  *(float4*)(xn + b*DIM + d) = acc;
}

// ---------------- K2: q[b,j] = (xn[b,:].qw[j,:] + qb[j]) / 8 ----------------
__global__ void k_q(const float* __restrict__ xn, const float* __restrict__ qw,
                    const float* __restrict__ qb, float* __restrict__ q){
  int wv = threadIdx.x >> 6, ln = threadIdx.x & 63;
  int j = blockIdx.x*4 + wv;
  float acc[BS] = {0,0,0,0,0,0,0,0};
  #pragma unroll
  for (int i=0; i<4; i++){
    int d = ln*4 + 256*i;
    float4 wt = *(const float4*)(qw + (size_t)j*DIM + d);
    #pragma unroll
    for (int b=0; b<BS; b++){
      float4 xv = *(const float4*)(xn + b*DIM + d);
      acc[b] += wt.x*xv.x + wt.y*xv.y + wt.z*xv.z + wt.w*xv.w;
    }
  }
  #pragma unroll
  for (int off=32; off>=1; off>>=1){
    #pragma unroll
    for (int b=0; b<BS; b++) acc[b] += __shfl_down(acc[b], off, 64);
  }
  if (ln == 0){
    float bias = qb[j];
    #pragma unroll
    for (int b=0; b<BS; b++) q[b*DIM + j] = (acc[b] + bias) * 0.125f;
  }
}

// ---------------- K3: p[b,h,d] = sum_j q[b,h*64+j]*kw[h*64+j,d] ----------------
// grid (4 dc, 16 h, 8 b), one output per thread; kw rows hit L2/L3 across b.
__global__ void k_p(const float* __restrict__ q, const float* __restrict__ kw,
                    float* __restrict__ p){
  int dc = blockIdx.x, h = blockIdx.y, b = blockIdx.z;
  int d = dc*256 + threadIdx.x;
  const float* qrow = q + b*DIM + h*HD;
  float acc = 0.f;
  #pragma unroll 8
  for (int j=0; j<HD; j++)
    acc += qrow[j] * kw[(size_t)(h*HD + j)*DIM + d];
  p[(size_t)(b*NH + h)*DIM + d] = acc;
}

// ---------------- K4: sc[b,h,s] += x[b,s,kc-chunk].p[b,h,kc-chunk]
// grid (16 s-chunks, 8 b, 4 kc), block 256 = 4 waves; wave g -> heads g*4..+3.
__global__ void k_scores(const float* __restrict__ x, const float* __restrict__ p,
                         float* __restrict__ sc){
  int s0 = blockIdx.x * 64;
  int b  = blockIdx.y;
  int kbase = blockIdx.z * 256;
  int tid = threadIdx.x;
  __shared__ float4 plds[256*5];      // [d][h/4] transposed p chunk (20 KB)
  __shared__ float  xlds[64*68];      // [s][d] 64x64 tile, pad 68 (17.4 KB)
  float* pf = (float*)plds;
  #pragma unroll
  for (int it=0; it<16; it++){        // stage p chunk: 256 d x 16 h
    int idx = it*256 + tid;
    int d = idx & 255, h = idx >> 8;
    pf[d*20 + h] = p[(size_t)(b*NH + h)*DIM + kbase + d];
  }
  int s = tid & 63, g = tid >> 6;     // wave-uniform g
  float acc[4] = {0.f,0.f,0.f,0.f};
  for (int dk=0; dk<4; dk++){
    __syncthreads();                  // p staged (dk=0) / prior xlds reads done
    #pragma unroll
    for (int it=0; it<4; it++){       // stage x tile 64 s x 64 d via float4
      int idx = it*256 + tid;
      int dd4 = idx & 15, ss = idx >> 4;
      float4 v = *(const float4*)(x + (size_t)(b*SEQ + s0 + ss)*DIM + kbase + dk*64 + dd4*4);
      *(float4*)(xlds + ss*68 + dd4*4) = v;
    }
    __syncthreads();
    #pragma unroll 4
    for (int dd4=0; dd4<16; dd4++){
      float4 xq = *(const float4*)(xlds + s*68 + dd4*4);   // b128, balanced banks
      int dbase = (dk*64 + dd4*4)*5 + g;
      float4 p0 = plds[dbase], p1 = plds[dbase+5], p2 = plds[dbase+10], p3 = plds[dbase+15];
      acc[0] += xq.x*p0.x + xq.y*p1.x + xq.z*p2.x + xq.w*p3.x;
      acc[1] += xq.x*p0.y + xq.y*p1.y + xq.z*p2.y + xq.w*p3.y;
      acc[2] += xq.x*p0.z + xq.y*p1.z + xq.z*p2.z + xq.w*p3.z;
      acc[3] += xq.x*p0.w + xq.y*p1.w + xq.z*p2.w + xq.w*p3.w;
    }
  }
  #pragma unroll
  for (int u=0; u<4; u++)
    atomicAdd(&sc[(size_t)(b*NH + g*4 + u)*SEQ + s0 + s], acc[u]);
}

// ---------------- K5: in-place softmax over s per (b,h) ----------------
__global__ void k_softmax(float* __restrict__ sc, const int* __restrict__ mask){
  int b = blockIdx.x >> 4, h = blockIdx.x & 15;
  int tid = threadIdx.x;
  float v[4];
  float mx = -3e38f;
  #pragma unroll
  for (int i=0; i<4; i++){
    int s = tid + 256*i;
    float v0 = sc[(size_t)(b*NH + h)*SEQ + s];
    if (mask[b*SEQ + s] == 0) v0 = -1e30f;
    v[i] = v0;
    mx = fmaxf(mx, v0);
  }
  #pragma unroll
  for (int off=32; off>=1; off>>=1) mx = fmaxf(mx, __shfl_xor(mx, off, 64));
  __shared__ float r1[4], r2[4];
  int wv = tid >> 6, ln = tid & 63;
  if (ln == 0) r1[wv] = mx;
  __syncthreads();
  mx = fmaxf(fmaxf(r1[0], r1[1]), fmaxf(r1[2], r1[3]));
  float sum = 0.f;
  #pragma unroll
  for (int i=0; i<4; i++){ v[i] = __expf(v[i] - mx); sum += v[i]; }
  #pragma unroll
  for (int off=32; off>=1; off>>=1) sum += __shfl_xor(sum, off, 64);
  if (ln == 0) r2[wv] = sum;
  __syncthreads();
  sum = r2[0] + r2[1] + r2[2] + r2[3];
  float inv = 1.f / sum;
  #pragma unroll
  for (int i=0; i<4; i++) sc[(size_t)(b*NH + h)*SEQ + tid + 256*i] = v[i] * inv;
}

// ---------------- K6: xw[b,h,d] += sum_{s chunk} w[b,h,s]*x[b,s,d] (atomic)
// grid (4 dc, 8 b, 16 sc), block 256 = 4 waves; wave wv -> heads wv*4..+3;
// lane ln -> 4 d. s-chunk 64. float4 x loads (16 B/lane).
__global__ void k_wpool(const float* __restrict__ x, const float* __restrict__ w,
                        float* __restrict__ xw){
  int dc = blockIdx.x, b = blockIdx.y, scn = blockIdx.z;
  int tid = threadIdx.x;
  __shared__ float4 wlds[64*5];       // [s][h/4] transposed weights (5 KB)
  float* wf = (float*)wlds;
  #pragma unroll
  for (int it=0; it<4; it++){         // stage 64 s x 16 h
    int idx = it*256 + tid;
    int ss = idx >> 4, hh = idx & 15;
    wf[ss*20 + hh] = w[(size_t)(b*NH + hh)*SEQ + scn*64 + ss];
  }
  __syncthreads();
  int ln = tid & 63, wv = tid >> 6;
  int d = dc*256 + ln*4;
  float4 a0={0,0,0,0}, a1={0,0,0,0}, a2={0,0,0,0}, a3={0,0,0,0};
  #pragma unroll 4
  for (int s=0; s<64; s++){
    float4 xq = *(const float4*)(x + (size_t)(b*SEQ + scn*64 + s)*DIM + d);
    float4 wq = wlds[s*5 + wv];       // wave-uniform broadcast
    a0.x+=xq.x*wq.x; a0.y+=xq.y*wq.x; a0.z+=xq.z*wq.x; a0.w+=xq.w*wq.x;
    a1.x+=xq.x*wq.y; a1.y+=xq.y*wq.y; a1.z+=xq.z*wq.y; a1.w+=xq.w*wq.y;
    a2.x+=xq.x*wq.z; a2.y+=xq.y*wq.z; a2.z+=xq.z*wq.z; a2.w+=xq.w*wq.z;
    a3.x+=xq.x*wq.w; a3.y+=xq.y*wq.w; a3.z+=xq.z*wq.w; a3.w+=xq.w*wq.w;
  }
  float4 a[4] = {a0,a1,a2,a3};
  #pragma unroll
  for (int u=0; u<4; u++){
    float* dst = xw + (size_t)(b*NH + wv*4 + u)*DIM + d;
    atomicAdd(dst+0, a[u].x); atomicAdd(dst+1, a[u].y);
    atomicAdd(dst+2, a[u].z); atomicAdd(dst+3, a[u].w);
  }
}

// ---------------- K7: ctx[b,jo] = xw[b,h(jo),:].vw[jo,:] + vb[jo] ----------------
__global__ void k_ctx(const float* __restrict__ xw, const float* __restrict__ vw,
                      const float* __restrict__ vb, float* __restrict__ ctx){
  int wv = threadIdx.x >> 6, ln = threadIdx.x & 63;
  int jo = blockIdx.x*4 + wv;
  int h  = jo >> 6;
  float acc[BS] = {0,0,0,0,0,0,0,0};
  #pragma unroll
  for (int i=0; i<4; i++){
    int d = ln*4 + 256*i;
    float4 vv = *(const float4*)(vw + (size_t)jo*DIM + d);
    #pragma unroll
    for (int b=0; b<BS; b++){
      float4 xv = *(const float4*)(xw + (size_t)(b*NH + h)*DIM + d);
      acc[b] += vv.x*xv.x + vv.y*xv.y + vv.z*xv.z + vv.w*xv.w;
    }
  }
  #pragma unroll
  for (int off=32; off>=1; off>>=1){
    #pragma unroll
    for (int b=0; b<BS; b++) acc[b] += __shfl_down(acc[b], off, 64);
  }
  if (ln == 0){
    float bias = vb[jo];
    #pragma unroll
    for (int b=0; b<BS; b++) ctx[b*DIM + jo] = acc[b] + bias;
  }
}

// ---------------- K8: out_row[b,i] = ctx[b,:].ow[i,:] + ob[i] ----------------
__global__ void k_outrow(const float* __restrict__ ctx, const float* __restrict__ ow,
                         const float* __restrict__ ob, float* __restrict__ outr){
  int wv = threadIdx.x >> 6, ln = threadIdx.x & 63;
  int io = blockIdx.x*4 + wv;
  float acc[BS] = {0,0,0,0,0,0,0,0};
  #pragma unroll
  for (int i=0; i<4; i++){
    int d = ln*4 + 256*i;
    float4 wt = *(const float4*)(ow + (size_t)io*DIM + d);
    #pragma unroll
    for (int b=0; b<BS; b++){
      float4 cv = *(const float4*)(ctx + b*DIM + d);
      acc[b] += wt.x*cv.x + wt.y*cv.y + wt.z*cv.z + wt.w*cv.w;
    }
  }
  #pragma unroll
  for (int off=32; off>=1; off>>=1){
    #pragma unroll
    for (int b=0; b<BS; b++) acc[b] += __shfl_down(acc[b], off, 64);
  }
  if (ln == 0){
    float bias = ob[io];
    #pragma unroll
    for (int b=0; b<BS; b++) outr[b*DIM + io] = acc[b] + bias;
  }
}

// ---------------- K9: out[b,s,:] = LN(out_row[b]+x[b,s,:])*g + beta ----------------
__global__ void k_ln(const float* __restrict__ x, const float* __restrict__ outr,
                     const float* __restrict__ g, const float* __restrict__ bt,
                     float* __restrict__ out){
  int row = blockIdx.x;
  int b = row >> 10;
  size_t base = (size_t)row * DIM;
  int tid = threadIdx.x;
  float4 xv = ((const float4*)(x + base))[tid];
  float4 ov = ((const float4*)(outr + (size_t)b*DIM))[tid];
  float4 h;
  h.x = xv.x + ov.x; h.y = xv.y + ov.y; h.z = xv.z + ov.z; h.w = xv.w + ov.w;
  float s  = h.x + h.y + h.z + h.w;
  float s2 = h.x*h.x + h.y*h.y + h.z*h.z + h.w*h.w;
  #pragma unroll
  for (int off=32; off>=1; off>>=1){
    s  += __shfl_xor(s,  off, 64);
    s2 += __shfl_xor(s2, off, 64);
  }
  __shared__ float r1[4], r2[4];
  int wv = tid >> 6, ln = tid & 63;
  if (ln == 0){ r1[wv] = s; r2[wv] = s2; }
  __syncthreads();
  s  = r1[0] + r1[1] + r1[2] + r1[3];
  s2 = r2[0] + r2[1] + r2[2] + r2[3];
  float mu   = s  * (1.f/1024.f);
  float var  = s2 * (1.f/1024.f) - mu*mu;
  float rstd = rsqrtf(var + 1e-12f);
  float4 gv = ((const float4*)g)[tid];
  float4 bv = ((const float4*)bt)[tid];
  float4 y;
  y.x = (h.x - mu)*rstd*gv.x + bv.x;
  y.y = (h.y - mu)*rstd*gv.y + bv.y;
  y.z = (h.z - mu)*rstd*gv.z + bv.z;
  y.w = (h.w - mu)*rstd*gv.w + bv.w;
  ((float4*)(out + base))[tid] = y;
}

extern "C" void kernel_launch(void* const* d_in, const int* in_sizes, int n_in,
                              void* d_out, int out_size, void* d_ws, size_t ws_size,
                              hipStream_t stream) {
  const float* x    = (const float*)d_in[0];
  const float* xnb  = (const float*)d_in[1];
  const int*   mask = (const int*  )d_in[2];
  const float* nm   = (const float*)d_in[3];
  const float* qw   = (const float*)d_in[4];
  const float* qb   = (const float*)d_in[5];
  const float* kw   = (const float*)d_in[6];
  // d_in[7] = kb: softmax-invariant constant, unused
  const float* vw   = (const float*)d_in[8];
  const float* vb   = (const float*)d_in[9];
  const float* ow   = (const float*)d_in[10];
  const float* ob   = (const float*)d_in[11];
  const float* lng  = (const float*)d_in[12];
  const float* lnb  = (const float*)d_in[13];
  float* out = (float*)d_out;

  float* ws   = (float*)d_ws;              // 425,984 floats = 1.63 MB total
  float* xn   = ws;                        // 8192
  float* q    = ws + 8192;                 // 8192
  float* p    = ws + 16384;                // 131072
  float* sc   = ws + 147456;               // 131072 (atomic accum; softmax in-place)
  float* xw   = ws + 278528;               // 131072 (atomic accum)
  float* ctx  = ws + 409600;               // 8192
  float* outr = ws + 417792;               // 8192

  k_zero   <<<256,             256, 0, stream>>>(sc);   // zeros sc..xw (contiguous 1 MB)
  k_pool   <<<BS,              256, 0, stream>>>(xnb, nm, xn);
  k_q      <<<256,             256, 0, stream>>>(xn, qw, qb, q);
  k_p      <<<dim3(4,NH,BS),   256, 0, stream>>>(q, kw, p);
  k_scores <<<dim3(16,BS,4),   256, 0, stream>>>(x, p, sc);
  k_softmax<<<BS*NH,           256, 0, stream>>>(sc, mask);
  k_wpool  <<<dim3(4,BS,16),   256, 0, stream>>>(x, sc, xw);
  k_ctx    <<<256,             256, 0, stream>>>(xw, vw, vb, ctx);
  k_outrow <<<256,             256, 0, stream>>>(ctx, ow, ob, outr);
  k_ln     <<<BS*SEQ,          256, 0, stream>>>(x, outr, lng, lnb, out);
}

// Round 5
// 170.640 us; speedup vs baseline: 1.3946x; 1.1679x over previous
//
#include <hip/hip_runtime.h>
#include <hip/hip_bf16.h>

// NeighborAttention on MI355X. fp32 in/out, int32 mask.
// KEY INSIGHT: query = broadcast of masked neighbor-mean -> all seq positions
// share one query per (b,h). Attention collapses:
//   scores[b,h,s] = x[b,s,:] . p[b,h,:],  p[b,h,:] = sum_j q[b,h,j]*kw[h*64+j,:]
//   ctx[b,h*64+j] = (sum_s w[b,h,s]*x[b,s,:]) . vw[h*64+j,:] + vb
//   out_row[b]    = ctx[b] @ ow.T + ob;  out = LN(out_row[b] + x[b,s,:])
// R4: R3's k_wpool (42us) was atomic-bound: WRITE_SIZE 33.5MB for a 0.5MB
// buffer = 2.1M fp32 atomicAdds writing through L2. This round: ZERO atomics.
// Score partials -> 4 kc-slabs (softmax sums them); wpool partials -> 16
// s-chunk slabs + tiny tree-reduce; 8-deep hoisted float4 loads for ILP.
// ws = 11.2 MB (calculated risk on ws_size).

#define DIM  1024
#define NH   16
#define HD   64
#define BS   8
#define SEQ  1024
#define NNB  50

// ---------------- K1: masked neighbor mean pool: xn[b,d] ----------------
__global__ void k_pool(const float* __restrict__ xnb, const float* __restrict__ nm,
                       float* __restrict__ xn){
  int b = blockIdx.x;
  int d = threadIdx.x*4;
  float4 acc = {0,0,0,0}; float wsum = 0.f;
  #pragma unroll 10
  for (int n=0; n<NNB; n++){
    float w = nm[b*NNB + n];
    float4 v = *(const float4*)(xnb + (size_t)(b*NNB + n)*DIM + d);
    acc.x += w*v.x; acc.y += w*v.y; acc.z += w*v.z; acc.w += w*v.w;
    wsum += w;
  }
  float inv = 1.f/wsum;
  acc.x*=inv; acc.y*=inv; acc.z*=inv; acc.w*=inv;
  *(float4*)(xn + b*DIM + d) = acc;
}

// ---------------- K2: q[b,j] = (xn[b,:].qw[j,:] + qb[j]) / 8 ----------------
__global__ void k_q(const float* __restrict__ xn, const float* __restrict__ qw,
                    const float* __restrict__ qb, float* __restrict__ q){
  int wv = threadIdx.x >> 6, ln = threadIdx.x & 63;
  int j = blockIdx.x*4 + wv;
  float acc[BS] = {0,0,0,0,0,0,0,0};
  #pragma unroll
  for (int i=0; i<4; i++){
    int d = ln*4 + 256*i;
    float4 wt = *(const float4*)(qw + (size_t)j*DIM + d);
    #pragma unroll
    for (int b=0; b<BS; b++){
      float4 xv = *(const float4*)(xn + b*DIM + d);
      acc[b] += wt.x*xv.x + wt.y*xv.y + wt.z*xv.z + wt.w*xv.w;
    }
  }
  #pragma unroll
  for (int off=32; off>=1; off>>=1){
    #pragma unroll
    for (int b=0; b<BS; b++) acc[b] += __shfl_down(acc[b], off, 64);
  }
  if (ln == 0){
    float bias = qb[j];
    #pragma unroll
    for (int b=0; b<BS; b++) q[b*DIM + j] = (acc[b] + bias) * 0.125f;
  }
}

// ---------------- K3: p[b,h,d] = sum_j q[b,h*64+j]*kw[h*64+j,d] ----------------
__global__ void k_p(const float* __restrict__ q, const float* __restrict__ kw,
                    float* __restrict__ p){
  int dc = blockIdx.x, h = blockIdx.y, b = blockIdx.z;
  int d = dc*256 + threadIdx.x;
  const float* qrow = q + b*DIM + h*HD;
  float acc = 0.f;
  #pragma unroll 8
  for (int j=0; j<HD; j++)
    acc += qrow[j] * kw[(size_t)(h*HD + j)*DIM + d];
  p[(size_t)(b*NH + h)*DIM + d] = acc;
}

// ---------------- K4: scp[kc][b,h,s] = x[b,s,kc-chunk].p[b,h,kc-chunk]
// grid (16 s-chunks, 8 b, 4 kc), block 256 = 4 waves; wave g -> heads g*4..+3.
// Plain slab stores (no atomics).
__global__ void k_scores(const float* __restrict__ x, const float* __restrict__ p,
                         float* __restrict__ scp){
  int s0 = blockIdx.x * 64;
  int b  = blockIdx.y;
  int kc = blockIdx.z;
  int kbase = kc * 256;
  int tid = threadIdx.x;
  __shared__ float4 plds[256*5];      // [d][h/4] transposed p chunk (20 KB)
  __shared__ float  xlds[64*68];      // [s][d] 64x64 tile, pad 68
  float* pf = (float*)plds;
  #pragma unroll
  for (int it=0; it<16; it++){        // stage p chunk: 256 d x 16 h
    int idx = it*256 + tid;
    int d = idx & 255, h = idx >> 8;
    pf[d*20 + h] = p[(size_t)(b*NH + h)*DIM + kbase + d];
  }
  int s = tid & 63, g = tid >> 6;     // wave-uniform g
  float acc[4] = {0.f,0.f,0.f,0.f};
  for (int dk=0; dk<4; dk++){
    __syncthreads();
    #pragma unroll
    for (int it=0; it<4; it++){       // stage x tile 64 s x 64 d via float4
      int idx = it*256 + tid;
      int dd4 = idx & 15, ss = idx >> 4;
      float4 v = *(const float4*)(x + (size_t)(b*SEQ + s0 + ss)*DIM + kbase + dk*64 + dd4*4);
      *(float4*)(xlds + ss*68 + dd4*4) = v;
    }
    __syncthreads();
    #pragma unroll 4
    for (int dd4=0; dd4<16; dd4++){
      float4 xq = *(const float4*)(xlds + s*68 + dd4*4);
      int dbase = (dk*64 + dd4*4)*5 + g;
      float4 p0 = plds[dbase], p1 = plds[dbase+5], p2 = plds[dbase+10], p3 = plds[dbase+15];
      acc[0] += xq.x*p0.x + xq.y*p1.x + xq.z*p2.x + xq.w*p3.x;
      acc[1] += xq.x*p0.y + xq.y*p1.y + xq.z*p2.y + xq.w*p3.y;
      acc[2] += xq.x*p0.z + xq.y*p1.z + xq.z*p2.z + xq.w*p3.z;
      acc[3] += xq.x*p0.w + xq.y*p1.w + xq.z*p2.w + xq.w*p3.w;
    }
  }
  float* slab = scp + (size_t)kc*(BS*NH*SEQ);
  #pragma unroll
  for (int u=0; u<4; u++)
    slab[(size_t)(b*NH + g*4 + u)*SEQ + s0 + s] = acc[u];
}

// ---------------- K5: softmax; sums 4 kc-slabs, writes weights into slab 0 ----
__global__ void k_softmax(float* __restrict__ scp, const int* __restrict__ mask){
  int b = blockIdx.x >> 4, h = blockIdx.x & 15;
  int tid = threadIdx.x;
  size_t rowoff = (size_t)(b*NH + h)*SEQ;
  float v[4];
  float mx = -3e38f;
  #pragma unroll
  for (int i=0; i<4; i++){
    int s = tid + 256*i;
    float v0 = 0.f;
    #pragma unroll
    for (int kc=0; kc<4; kc++) v0 += scp[(size_t)kc*(BS*NH*SEQ) + rowoff + s];
    if (mask[b*SEQ + s] == 0) v0 = -1e30f;
    v[i] = v0;
    mx = fmaxf(mx, v0);
  }
  #pragma unroll
  for (int off=32; off>=1; off>>=1) mx = fmaxf(mx, __shfl_xor(mx, off, 64));
  __shared__ float r1[4], r2[4];
  int wv = tid >> 6, ln = tid & 63;
  if (ln == 0) r1[wv] = mx;
  __syncthreads();
  mx = fmaxf(fmaxf(r1[0], r1[1]), fmaxf(r1[2], r1[3]));
  float sum = 0.f;
  #pragma unroll
  for (int i=0; i<4; i++){ v[i] = __expf(v[i] - mx); sum += v[i]; }
  #pragma unroll
  for (int off=32; off>=1; off>>=1) sum += __shfl_xor(sum, off, 64);
  if (ln == 0) r2[wv] = sum;
  __syncthreads();
  sum = r2[0] + r2[1] + r2[2] + r2[3];
  float inv = 1.f / sum;
  #pragma unroll
  for (int i=0; i<4; i++) scp[rowoff + tid + 256*i] = v[i] * inv;   // slab 0 = w
}

// ---------------- K6: xwp[scn][b,h,d] = sum_{s in chunk} w[b,h,s]*x[b,s,d]
// grid (4 dc, 8 b, 16 scn), block 256 = 4 waves; wave wv -> heads wv*4..+3;
// lane -> 4 d. s-chunk 64. 8-deep hoisted float4 loads, plain slab stores.
__global__ void k_wpool(const float* __restrict__ x, const float* __restrict__ w,
                        float* __restrict__ xwp){
  int dc = blockIdx.x, b = blockIdx.y, scn = blockIdx.z;
  int tid = threadIdx.x;
  __shared__ float4 wlds[64*5];       // [s][h/4] transposed weights (5 KB)
  float* wf = (float*)wlds;
  #pragma unroll
  for (int it=0; it<4; it++){         // stage 64 s x 16 h
    int idx = it*256 + tid;
    int ss = idx >> 4, hh = idx & 15;
    wf[ss*20 + hh] = w[(size_t)(b*NH + hh)*SEQ + scn*64 + ss];
  }
  __syncthreads();
  int ln = tid & 63, wv = tid >> 6;
  int d = dc*256 + ln*4;
  const float* xbase = x + (size_t)(b*SEQ + scn*64)*DIM + d;
  float4 a0={0,0,0,0}, a1={0,0,0,0}, a2={0,0,0,0}, a3={0,0,0,0};
  for (int sb=0; sb<64; sb+=8){
    float4 xq[8];
    #pragma unroll
    for (int u=0; u<8; u++)
      xq[u] = *(const float4*)(xbase + (size_t)(sb+u)*DIM);   // 8 loads in flight
    #pragma unroll
    for (int u=0; u<8; u++){
      float4 wq = wlds[(sb+u)*5 + wv];  // wave-uniform broadcast
      a0.x+=xq[u].x*wq.x; a0.y+=xq[u].y*wq.x; a0.z+=xq[u].z*wq.x; a0.w+=xq[u].w*wq.x;
      a1.x+=xq[u].x*wq.y; a1.y+=xq[u].y*wq.y; a1.z+=xq[u].z*wq.y; a1.w+=xq[u].w*wq.y;
      a2.x+=xq[u].x*wq.z; a2.y+=xq[u].y*wq.z; a2.z+=xq[u].z*wq.z; a2.w+=xq[u].w*wq.z;
      a3.x+=xq[u].x*wq.w; a3.y+=xq[u].y*wq.w; a3.z+=xq[u].z*wq.w; a3.w+=xq[u].w*wq.w;
    }
  }
  float* dst = xwp + (size_t)scn*(BS*NH*DIM) + (size_t)(b*NH + wv*4)*DIM + d;
  *(float4*)(dst          ) = a0;
  *(float4*)(dst +   DIM  ) = a1;
  *(float4*)(dst + 2*DIM  ) = a2;
  *(float4*)(dst + 3*DIM  ) = a3;
}

// ---------------- K6b: xw[b,h,d] = sum_{scn<16} xwp[scn][b,h,d] ----------------
__global__ void k_xwred(const float* __restrict__ xwp, float* __restrict__ xw){
  int id = blockIdx.x*256 + threadIdx.x;     // 512 blocks -> 131072 ids
  float v = 0.f;
  #pragma unroll
  for (int scn=0; scn<16; scn++) v += xwp[(size_t)scn*(BS*NH*DIM) + id];
  xw[id] = v;
}

// ---------------- K7: ctx[b,jo] = xw[b,h(jo),:].vw[jo,:] + vb[jo] ----------------
__global__ void k_ctx(const float* __restrict__ xw, const float* __restrict__ vw,
                      const float* __restrict__ vb, float* __restrict__ ctx){
  int wv = threadIdx.x >> 6, ln = threadIdx.x & 63;
  int jo = blockIdx.x*4 + wv;
  int h  = jo >> 6;
  float acc[BS] = {0,0,0,0,0,0,0,0};
  #pragma unroll
  for (int i=0; i<4; i++){
    int d = ln*4 + 256*i;
    float4 vv = *(const float4*)(vw + (size_t)jo*DIM + d);
    #pragma unroll
    for (int b=0; b<BS; b++){
      float4 xv = *(const float4*)(xw + (size_t)(b*NH + h)*DIM + d);
      acc[b] += vv.x*xv.x + vv.y*xv.y + vv.z*xv.z + vv.w*xv.w;
    }
  }
  #pragma unroll
  for (int off=32; off>=1; off>>=1){
    #pragma unroll
    for (int b=0; b<BS; b++) acc[b] += __shfl_down(acc[b], off, 64);
  }
  if (ln == 0){
    float bias = vb[jo];
    #pragma unroll
    for (int b=0; b<BS; b++) ctx[b*DIM + jo] = acc[b] + bias;
  }
}

// ---------------- K8: out_row[b,i] = ctx[b,:].ow[i,:] + ob[i] ----------------
__global__ void k_outrow(const float* __restrict__ ctx, const float* __restrict__ ow,
                         const float* __restrict__ ob, float* __restrict__ outr){
  int wv = threadIdx.x >> 6, ln = threadIdx.x & 63;
  int io = blockIdx.x*4 + wv;
  float acc[BS] = {0,0,0,0,0,0,0,0};
  #pragma unroll
  for (int i=0; i<4; i++){
    int d = ln*4 + 256*i;
    float4 wt = *(const float4*)(ow + (size_t)io*DIM + d);
    #pragma unroll
    for (int b=0; b<BS; b++){
      float4 cv = *(const float4*)(ctx + b*DIM + d);
      acc[b] += wt.x*cv.x + wt.y*cv.y + wt.z*cv.z + wt.w*cv.w;
    }
  }
  #pragma unroll
  for (int off=32; off>=1; off>>=1){
    #pragma unroll
    for (int b=0; b<BS; b++) acc[b] += __shfl_down(acc[b], off, 64);
  }
  if (ln == 0){
    float bias = ob[io];
    #pragma unroll
    for (int b=0; b<BS; b++) outr[b*DIM + io] = acc[b] + bias;
  }
}

// ---------------- K9: out[b,s,:] = LN(out_row[b]+x[b,s,:])*g + beta ----------------
__global__ void k_ln(const float* __restrict__ x, const float* __restrict__ outr,
                     const float* __restrict__ g, const float* __restrict__ bt,
                     float* __restrict__ out){
  int row = blockIdx.x;
  int b = row >> 10;
  size_t base = (size_t)row * DIM;
  int tid = threadIdx.x;
  float4 xv = ((const float4*)(x + base))[tid];
  float4 ov = ((const float4*)(outr + (size_t)b*DIM))[tid];
  float4 h;
  h.x = xv.x + ov.x; h.y = xv.y + ov.y; h.z = xv.z + ov.z; h.w = xv.w + ov.w;
  float s  = h.x + h.y + h.z + h.w;
  float s2 = h.x*h.x + h.y*h.y + h.z*h.z + h.w*h.w;
  #pragma unroll
  for (int off=32; off>=1; off>>=1){
    s  += __shfl_xor(s,  off, 64);
    s2 += __shfl_xor(s2, off, 64);
  }
  __shared__ float r1[4], r2[4];
  int wv = tid >> 6, ln = tid & 63;
  if (ln == 0){ r1[wv] = s; r2[wv] = s2; }
  __syncthreads();
  s  = r1[0] + r1[1] + r1[2] + r1[3];
  s2 = r2[0] + r2[1] + r2[2] + r2[3];
  float mu   = s  * (1.f/1024.f);
  float var  = s2 * (1.f/1024.f) - mu*mu;
  float rstd = rsqrtf(var + 1e-12f);
  float4 gv = ((const float4*)g)[tid];
  float4 bv = ((const float4*)bt)[tid];
  float4 y;
  y.x = (h.x - mu)*rstd*gv.x + bv.x;
  y.y = (h.y - mu)*rstd*gv.y + bv.y;
  y.z = (h.z - mu)*rstd*gv.z + bv.z;
  y.w = (h.w - mu)*rstd*gv.w + bv.w;
  ((float4*)(out + base))[tid] = y;
}

extern "C" void kernel_launch(void* const* d_in, const int* in_sizes, int n_in,
                              void* d_out, int out_size, void* d_ws, size_t ws_size,
                              hipStream_t stream) {
  const float* x    = (const float*)d_in[0];
  const float* xnb  = (const float*)d_in[1];
  const int*   mask = (const int*  )d_in[2];
  const float* nm   = (const float*)d_in[3];
  const float* qw   = (const float*)d_in[4];
  const float* qb   = (const float*)d_in[5];
  const float* kw   = (const float*)d_in[6];
  // d_in[7] = kb: softmax-invariant constant, unused
  const float* vw   = (const float*)d_in[8];
  const float* vb   = (const float*)d_in[9];
  const float* ow   = (const float*)d_in[10];
  const float* ob   = (const float*)d_in[11];
  const float* lng  = (const float*)d_in[12];
  const float* lnb  = (const float*)d_in[13];
  float* out = (float*)d_out;

  float* ws   = (float*)d_ws;              // 2,785,280 floats = 11.2 MB
  float* xn   = ws;                        // 8192
  float* q    = ws + 8192;                 // 8192
  float* p    = ws + 16384;                // 131072 (reused as xw after k_scores)
  float* scp  = ws + 147456;               // 4 slabs x 131072 (slab0 -> weights)
  float* xwp  = ws + 671744;               // 16 slabs x 131072 = 8 MB
  float* ctx  = ws + 2768896;              // 8192
  float* outr = ws + 2777088;              // 8192
  float* xw   = p;                         // alias: p dead after k_scores

  k_pool   <<<BS,              256, 0, stream>>>(xnb, nm, xn);
  k_q      <<<256,             256, 0, stream>>>(xn, qw, qb, q);
  k_p      <<<dim3(4,NH,BS),   256, 0, stream>>>(q, kw, p);
  k_scores <<<dim3(16,BS,4),   256, 0, stream>>>(x, p, scp);
  k_softmax<<<BS*NH,           256, 0, stream>>>(scp, mask);
  k_wpool  <<<dim3(4,BS,16),   256, 0, stream>>>(x, scp, xwp);
  k_xwred  <<<512,             256, 0, stream>>>(xwp, xw);
  k_ctx    <<<256,             256, 0, stream>>>(xw, vw, vb, ctx);
  k_outrow <<<256,             256, 0, stream>>>(ctx, ow, ob, outr);
  k_ln     <<<BS*SEQ,          256, 0, stream>>>(x, outr, lng, lnb, out);
}